// Round 1
// baseline (316.658 us; speedup 1.0000x reference)
//
#include <hip/hip_runtime.h>
#include <hip/hip_bf16.h>

// ObjectRelationNetwork on MI355X.
// Factorization: h[p=(i,j)] = relu(U'[i] + V[j]) with U' = O@W1a^T + b1, V = O@W1b^T.
// Layer 2 (the real work, 32 GFLOP) via bf16 MFMA 16x16x32; output e (252 MB fp32)
// write is the roofline (~40 us at 6.3 TB/s).

typedef __attribute__((ext_vector_type(8))) short bf16x8;   // 8 bf16 = 4 VGPRs
typedef __attribute__((ext_vector_type(4))) float f32x4;    // MFMA C/D

#define MFMA16(a, b, c) __builtin_amdgcn_mfma_f32_16x16x32_bf16((a), (b), (c), 0, 0, 0)

#define E_ELEMS 62914560ull   // 240*1024*256 (e output), then 245760 all_is_obj floats

__device__ __forceinline__ short f2bf(float f) {          // RNE float->bf16
  unsigned u = __builtin_bit_cast(unsigned, f);
  u += 0x7fffu + ((u >> 16) & 1u);
  return (short)(u >> 16);
}
__device__ __forceinline__ float bf2f(short s) {
  unsigned u = ((unsigned)(unsigned short)s) << 16;
  return __builtin_bit_cast(float, u);
}

// ---- prep: W2 (256x256 fp32, row o, col k) -> bf16 B-fragment layout W2L[k>>3][n][k&7]
__global__ void prep_w2(const float* __restrict__ W2, short* __restrict__ W2L) {
  int t = blockIdx.x * 256 + threadIdx.x;   // 0..8191, t == kb*256 + n
  int kb = t >> 8;
  int n  = t & 255;
  const float* p = W2 + (size_t)n * 256 + kb * 8;
  float4 x = *(const float4*)p;
  float4 y = *(const float4*)(p + 4);
  bf16x8 f;
  f[0] = f2bf(x.x); f[1] = f2bf(x.y); f[2] = f2bf(x.z); f[3] = f2bf(x.w);
  f[4] = f2bf(y.x); f[5] = f2bf(y.y); f[6] = f2bf(y.z); f[7] = f2bf(y.w);
  *(bf16x8*)&W2L[(size_t)t * 8] = f;        // contiguous coalesced store
}

// ---- main: 960 blocks (4 per (b,t)), 256 threads (4 waves). LDS exactly 64 KB -> 2 WG/CU.
__global__ __launch_bounds__(256) void orn_main(
    const float* __restrict__ objs, const float* __restrict__ W1,
    const float* __restrict__ b1, const float* __restrict__ b2,
    const short* __restrict__ W2L, float* __restrict__ out) {
  __shared__ short ULs[32 * 32 * 8];   // [kb=o>>3][i][o&7]  bf16 of U'=U+b1   (16 KB)
  __shared__ short VLs[32 * 32 * 8];   // [kb][j][jj]                          (16 KB)
  __shared__ short hL[32 * 64 * 8];    // [kb][m(64 rows)][jj]  h-tile         (32 KB)

  float* psum  = (float*)hL;           // phase-1 scratch aliases hL
  float* fclip = ((float*)hL) + 256;

  const int tid = threadIdx.x;
  const int bid = blockIdx.x;
  const int bt  = bid >> 2;            // 0..239
  const int q   = bid & 3;             // row-quarter of this slab
  const int b   = bt / 15;
  const int tm  = bt - b * 15;         // t-1
  const float* O = objs + (size_t)(b * 16 + tm + 1) * (32 * 128);

  const int lane = tid & 63;
  const int w    = tid >> 6;           // wave 0..3
  const int l15  = lane & 15;
  const int quad = lane >> 4;
  const int n0   = w * 64;             // this wave's output-col base (N split 4x64)

  // ---------------- Phase 1: fp32 row sums -> all_is_obj (output 1) ----------------
  {
    int i = tid >> 3, c = tid & 7;
    const float* p = O + i * 128 + c * 16;
    float s = 0.f;
#pragma unroll
    for (int e = 0; e < 4; e++) {
      float4 v = *(const float4*)(p + e * 4);
      s += v.x + v.y + v.z + v.w;
    }
    psum[tid] = s;
  }
  __syncthreads();
  if (tid < 32) {
    float s = 0.f;
#pragma unroll
    for (int c = 0; c < 8; c++) s += psum[tid * 8 + c];
    fclip[tid] = fminf(fmaxf(s, 0.f), 1.f);
  }
  __syncthreads();
  {
    int p = q * 256 + tid;             // this WG's 256 pairs
    int i = p >> 5, j = p & 31;
    float v = fclip[i] * fclip[j] * (float)(tm + 1);
    out[E_ELEMS + (size_t)bt * 1024 + p] = fminf(fmaxf(v, 0.f), 1.f);
  }

  // ---------------- Phase 2: U' and V (32x256 each) via MFMA, bf16 into LDS --------
  {
    // A-fragments from O (M=32,K=128): A[m=l15+16*ms][k=ks*32+quad*8+jj]
    bf16x8 afr[2][4];
#pragma unroll
    for (int ms = 0; ms < 2; ms++)
#pragma unroll
      for (int ks = 0; ks < 4; ks++) {
        const float* p = O + (ms * 16 + l15) * 128 + ks * 32 + quad * 8;
        float4 x = *(const float4*)p;
        float4 y = *(const float4*)(p + 4);
        bf16x8 f;
        f[0] = f2bf(x.x); f[1] = f2bf(x.y); f[2] = f2bf(x.z); f[3] = f2bf(x.w);
        f[4] = f2bf(y.x); f[5] = f2bf(y.y); f[6] = f2bf(y.z); f[7] = f2bf(y.w);
        afr[ms][ks] = f;
      }
    const f32x4 zf = {0.f, 0.f, 0.f, 0.f};
    f32x4 accU[2][4], accV[2][4];
#pragma unroll
    for (int ms = 0; ms < 2; ms++)
#pragma unroll
      for (int ns = 0; ns < 4; ns++) { accU[ms][ns] = zf; accV[ms][ns] = zf; }
#pragma unroll
    for (int ks = 0; ks < 4; ks++) {
#pragma unroll
      for (int ns = 0; ns < 4; ns++) {
        // B[k][n] = W1[o=n][d=k] (U) / W1[o][128+d] (V); 8 consecutive d per lane
        const float* pu = W1 + (size_t)(n0 + ns * 16 + l15) * 256 + ks * 32 + quad * 8;
        float4 xu = *(const float4*)pu;
        float4 yu = *(const float4*)(pu + 4);
        float4 xv = *(const float4*)(pu + 128);
        float4 yv = *(const float4*)(pu + 132);
        bf16x8 bu, bv;
        bu[0] = f2bf(xu.x); bu[1] = f2bf(xu.y); bu[2] = f2bf(xu.z); bu[3] = f2bf(xu.w);
        bu[4] = f2bf(yu.x); bu[5] = f2bf(yu.y); bu[6] = f2bf(yu.z); bu[7] = f2bf(yu.w);
        bv[0] = f2bf(xv.x); bv[1] = f2bf(xv.y); bv[2] = f2bf(xv.z); bv[3] = f2bf(xv.w);
        bv[4] = f2bf(yv.x); bv[5] = f2bf(yv.y); bv[6] = f2bf(yv.z); bv[7] = f2bf(yv.w);
#pragma unroll
        for (int ms = 0; ms < 2; ms++) {
          accU[ms][ns] = MFMA16(afr[ms][ks], bu, accU[ms][ns]);
          accV[ms][ns] = MFMA16(afr[ms][ks], bv, accV[ms][ns]);
        }
      }
    }
    // C/D layout: col = l15 (o-part), row = quad*4 + r (i-part). Fold b1 into U'.
#pragma unroll
    for (int ms = 0; ms < 2; ms++)
#pragma unroll
      for (int ns = 0; ns < 4; ns++) {
        int o  = n0 + ns * 16 + l15;
        float bb = b1[o];
        int kb = o >> 3, jj = o & 7;
#pragma unroll
        for (int r = 0; r < 4; r++) {
          int i = ms * 16 + quad * 4 + r;
          ULs[(kb * 32 + i) * 8 + jj] = f2bf(accU[ms][ns][r] + bb);
          VLs[(kb * 32 + i) * 8 + jj] = f2bf(accV[ms][ns][r]);
        }
      }
  }

  float b2r[4];
#pragma unroll
  for (int ns = 0; ns < 4; ns++) b2r[ns] = b2[n0 + ns * 16 + l15];

  const int R0 = q * 256;              // this WG's row base within the slab
  const f32x4 zf = {0.f, 0.f, 0.f, 0.f};

#pragma unroll 1
  for (int c = 0; c < 4; c++) {        // 4 chunks of 64 pair-rows
    __syncthreads();                   // phase-2 writes / previous GEMM reads done
    {
      // build h-tile: lanes -> consecutive m: VLs read 512B-contiguous, ULs broadcast,
      // hL write 1KB-contiguous — all conflict-free.
      int m = tid & 63;
      int kbase = tid >> 6;
      int i = ((R0 + c * 64) >> 5) + (m >> 5);
      int j = m & 31;
#pragma unroll
      for (int s = 0; s < 8; s++) {
        int kb = kbase + s * 4;
        bf16x8 u = *(bf16x8*)&ULs[(kb * 32 + i) * 8];
        bf16x8 v = *(bf16x8*)&VLs[(kb * 32 + j) * 8];
        bf16x8 hh;
#pragma unroll
        for (int e = 0; e < 8; e++) {
          float f = bf2f(u[e]) + bf2f(v[e]);
          hh[e] = f2bf(fmaxf(f, 0.f));
        }
        *(bf16x8*)&hL[(kb * 64 + m) * 8] = hh;
      }
    }
    __syncthreads();

    // GEMM: wave-tile 64(M) x 64(N), K=256 in 8 steps of 32
    f32x4 acc[4][4];
#pragma unroll
    for (int ms = 0; ms < 4; ms++)
#pragma unroll
      for (int ns = 0; ns < 4; ns++) acc[ms][ns] = zf;
#pragma unroll
    for (int ks = 0; ks < 8; ks++) {
      int kb = ks * 4 + quad;
      bf16x8 af[4];
#pragma unroll
      for (int ms = 0; ms < 4; ms++)
        af[ms] = *(bf16x8*)&hL[(kb * 64 + ms * 16 + l15) * 8];
#pragma unroll
      for (int ns = 0; ns < 4; ns++) {
        bf16x8 bfb = *(const bf16x8*)&W2L[((size_t)kb * 256 + n0 + ns * 16 + l15) * 8];
#pragma unroll
        for (int ms = 0; ms < 4; ms++)
          acc[ms][ns] = MFMA16(af[ms], bfb, acc[ms][ns]);
      }
    }

    // epilogue: bias + relu + store (16 lanes write 64B-contiguous runs)
    size_t rowbase = (size_t)bt * 1024 + R0 + c * 64;
#pragma unroll
    for (int ms = 0; ms < 4; ms++)
#pragma unroll
      for (int ns = 0; ns < 4; ns++) {
        int o = n0 + ns * 16 + l15;
#pragma unroll
        for (int r = 0; r < 4; r++) {
          int lr = ms * 16 + quad * 4 + r;
          out[(rowbase + lr) * 256 + o] = fmaxf(acc[ms][ns][r] + b2r[ns], 0.f);
        }
      }
  }
}

extern "C" void kernel_launch(void* const* d_in, const int* in_sizes, int n_in,
                              void* d_out, int out_size, void* d_ws, size_t ws_size,
                              hipStream_t stream) {
  const float* objs = (const float*)d_in[0];
  const float* W1   = (const float*)d_in[1];
  const float* b1   = (const float*)d_in[2];
  const float* W2   = (const float*)d_in[3];
  const float* b2   = (const float*)d_in[4];
  float* out = (float*)d_out;
  short* W2L = (short*)d_ws;           // 128 KB bf16 swizzled W2

  prep_w2<<<32, 256, 0, stream>>>(W2, W2L);
  orn_main<<<960, 256, 0, stream>>>(objs, W1, b1, b2, W2L, out);
}